// Round 1
// baseline (116.398 us; speedup 1.0000x reference)
//
#include <hip/hip_runtime.h>

#define L_N    50000
#define K_DIM  512
#define C_DIM  32
#define NROWS  64
#define KC     16
#define NCHUNK (K_DIM / KC)                 // 32
#define NBLK   ((L_N + NROWS - 1) / NROWS)  // 782

// ws layout (floats): [0] = sum exp(s)   [1..32] = sum exp(s)*emb[c]
__global__ __launch_bounds__(256, 4) void k_main(
    const float* __restrict__ other,   // [L][512]
    const float* __restrict__ W12,     // [32][512]
    const float* __restrict__ b12,     // [32]
    const float* __restrict__ Wa,      // [96], we use [64..95]
    float* __restrict__ ws)
{
    __shared__ float xs[NROWS * KC];   // 4 KB staging tile
    __shared__ float sred[4][NROWS];   // per-wave score partials
    __shared__ float pbuf[NROWS];      // exp weights broadcast

    const int tid  = threadIdx.x;
    const int lane = tid & 63;
    const int wv   = tid >> 6;
    // wave-uniform channel base -> forces SGPR path for W12 loads
    const int c0   = __builtin_amdgcn_readfirstlane(wv << 3);
    const int row0 = blockIdx.x * NROWS;

    // ---- staging source (dest slot d = tid*4 floats, linear for global_load_lds) ----
    const int srow  = tid >> 2;              // 0..63
    const int kslot = (tid & 3) << 2;        // 0,4,8,12
    const int ssw   = ((srow >> 2) & 3) << 2;
    int grow = row0 + srow; if (grow >= L_N) grow = L_N - 1;   // clamp tail
    const float* gsrc = other + (size_t)grow * K_DIM + (kslot ^ ssw);

    // read-side swizzle for this lane's row
    const int rsw = ((lane >> 2) & 3) << 2;

    float acc[8] = {0.f,0.f,0.f,0.f,0.f,0.f,0.f,0.f};

    for (int ck = 0; ck < NCHUNK; ++ck) {
        const int k0 = ck * KC;
        __builtin_amdgcn_global_load_lds(
            (const __attribute__((address_space(1))) void*)(gsrc + k0),
            (__attribute__((address_space(3))) void*)(xs + tid * 4),
            16, 0, 0);
        __syncthreads();   // compiler drains vmcnt before barrier -> tile ready
        #pragma unroll
        for (int kk4 = 0; kk4 < 4; ++kk4) {
            const int kk = kk4 << 2;
            const float4 xv = *(const float4*)&xs[lane * KC + (kk ^ rsw)];
            #pragma unroll
            for (int j = 0; j < 8; ++j) {
                const float4 wvv = *(const float4*)&W12[(size_t)(c0 + j) * K_DIM + k0 + kk];
                acc[j] = fmaf(xv.x, wvv.x, acc[j]);
                acc[j] = fmaf(xv.y, wvv.y, acc[j]);
                acc[j] = fmaf(xv.z, wvv.z, acc[j]);
                acc[j] = fmaf(xv.w, wvv.w, acc[j]);
            }
        }
        __syncthreads();   // protect xs before next chunk's staging
    }

    // ---- bias + score partial for this wave's 8 channels ----
    float sc = 0.f;
    #pragma unroll
    for (int j = 0; j < 8; ++j) {
        acc[j] += b12[c0 + j];                       // emb (pre-relu) for weighting
        sc = fmaf(fmaxf(acc[j], 0.f), Wa[64 + c0 + j], sc);  // relu(emb)·Wa_e
    }
    sred[wv][lane] = sc;
    __syncthreads();

    if (wv == 0) {
        const float s = sred[0][lane] + sred[1][lane] + sred[2][lane] + sred[3][lane];
        // no max-subtraction: scores are O(1) by construction (softmax shift-invariance
        // already removed the rx·Wa and ba terms)
        const float p = (row0 + lane < L_N) ? __expf(s) : 0.f;
        pbuf[lane] = p;
    }
    __syncthreads();
    const float p = pbuf[lane];

    // ---- weighted emb accumulation: butterfly all-reduce over 64 lanes ----
    float wacc[8];
    #pragma unroll
    for (int j = 0; j < 8; ++j) wacc[j] = p * acc[j];
    #pragma unroll
    for (int d = 1; d < 64; d <<= 1) {
        #pragma unroll
        for (int j = 0; j < 8; ++j) wacc[j] += __shfl_xor(wacc[j], d);
    }
    if (lane < 8) {
        float v = 0.f;
        #pragma unroll
        for (int j = 0; j < 8; ++j) v = (lane == j) ? wacc[j] : v;  // static idx only
        atomicAdd(ws + 1 + c0 + lane, v);
    }
    if (wv == 0) {
        float l = p;
        #pragma unroll
        for (int d = 1; d < 64; d <<= 1) l += __shfl_xor(l, d);
        if (lane == 0) atomicAdd(ws, l);
    }
}

__global__ __launch_bounds__(256) void k_final(
    const float* __restrict__ ws,
    const float* __restrict__ inputs,   // [256]
    const float* __restrict__ act_idx,  // [64]
    const float* __restrict__ W11, const float* __restrict__ b11,
    const float* __restrict__ Wao, const float* __restrict__ bao,
    const float* __restrict__ W2,  const float* __restrict__ b2,
    const float* __restrict__ W3,  const float* __restrict__ b3,
    float* __restrict__ out)            // [33]: r, samples[32]
{
    __shared__ float rm[32];      // relu(mixed)
    __shared__ float z[32];       // attn_out logits
    __shared__ float xcat[96];    // relu([input_x ; one_hot])
    __shared__ float h64[64];
    __shared__ int   amax;

    const int t  = threadIdx.x;
    const int hh = t >> 2, q = t & 3;

    if (t < 32) rm[t] = fmaxf(ws[1 + t] / ws[0], 0.f);

    // input_x partial: 4 threads per output h, 80 k each
    float bp = 0.f;
    for (int i = 0; i < 80; ++i) {
        const int k = q * 80 + i;
        const float xv = (k < 256) ? inputs[k] : act_idx[k - 256];
        bp = fmaf(W11[hh * 320 + k], xv, bp);
    }
    bp += __shfl_xor(bp, 1);
    bp += __shfl_xor(bp, 2);
    __syncthreads();   // rm ready

    if (t < 32) {
        float zz = bao[t];
        for (int d = 0; d < 32; ++d) zz = fmaf(Wao[t * 32 + d], rm[d], zz);
        z[t] = zz;
    }
    __syncthreads();
    if (t == 0) {
        int bi = 0; float bv = z[0];
        for (int c = 1; c < 32; ++c) { if (z[c] > bv) { bv = z[c]; bi = c; } }
        amax = bi;   // first-max tiebreak, matches jnp.argmax
    }
    __syncthreads();
    if (q == 0) xcat[hh] = fmaxf(bp + b11[hh], 0.f);
    if (t < 32) xcat[64 + t] = (t == amax) ? 1.f : 0.f;  // one_hot_st == samples
    __syncthreads();

    float dp = 0.f;
    for (int i = 0; i < 24; ++i) {
        const int k = q * 24 + i;
        dp = fmaf(W2[hh * 96 + k], xcat[k], dp);
    }
    dp += __shfl_xor(dp, 1);
    dp += __shfl_xor(dp, 2);
    if (q == 0) h64[hh] = fmaxf(dp + b2[hh], 0.f);
    __syncthreads();

    if (t == 0) {
        float r = b3[0];
        for (int i = 0; i < 64; ++i) r = fmaf(W3[i], h64[i], r);
        out[0] = r;
    }
    if (t < 32) out[1 + t] = (t == amax) ? 1.f : 0.f;
}

extern "C" void kernel_launch(void* const* d_in, const int* in_sizes, int n_in,
                              void* d_out, int out_size, void* d_ws, size_t ws_size,
                              hipStream_t stream) {
    const float* inputs  = (const float*)d_in[0];
    const float* act_idx = (const float*)d_in[1];
    const float* other   = (const float*)d_in[2];
    const float* W11     = (const float*)d_in[3];
    const float* b11     = (const float*)d_in[4];
    const float* W12     = (const float*)d_in[5];
    const float* b12     = (const float*)d_in[6];
    const float* Wa      = (const float*)d_in[7];
    // d_in[8] = ba : unused (softmax shift-invariant)
    const float* Wao     = (const float*)d_in[9];
    const float* bao     = (const float*)d_in[10];
    const float* W2      = (const float*)d_in[11];
    const float* b2      = (const float*)d_in[12];
    const float* W3      = (const float*)d_in[13];
    const float* b3      = (const float*)d_in[14];
    float* ws = (float*)d_ws;

    hipMemsetAsync(ws, 0, 33 * sizeof(float), stream);
    k_main<<<NBLK, 256, 0, stream>>>(other, W12, b12, Wa, ws);
    k_final<<<1, 256, 0, stream>>>(ws, inputs, act_idx, W11, b11,
                                   Wao, bao, W2, b2, W3, b3, (float*)d_out);
}